// Round 2
// baseline (113.672 us; speedup 1.0000x reference)
//
#include <hip/hip_runtime.h>
#include <math.h>

#define N_NODES 8192
#define F_IN    256
#define F_OUT   128
#define DEG     32
#define ALPHA   0.2f

#define MT      32            // rows per block (kernel A)
#define KC      64            // k-chunk
#define HPAD    68            // h_tile row stride in floats (272 B, 16B-aligned)

// ---- Kernel A: hW = h @ W  (f32 register-tiled) + fused h1/h2 epilogue ------
// grid 256 blocks x 256 threads; block computes 32 rows x 128 cols.
// thread: 4 rows x 4 cols. LDS: h_tile[32][68] + W_tile[64][128] = ~41.5 KB.
__global__ __launch_bounds__(256) void gemm_fused_kernel(
        const float* __restrict__ h,
        const float* __restrict__ W,
        const float* __restrict__ a,
        float* __restrict__ hW,
        float* __restrict__ h1,
        float* __restrict__ h2) {
    __shared__ float h_tile[MT * HPAD];        // row-major, pad to 68
    __shared__ float W_tile[KC * F_OUT];

    const int tid  = threadIdx.x;
    const int row0 = blockIdx.x * MT;
    const int c0   = (tid & 31) * 4;           // col group (float4)
    const int r0   = (tid >> 5) * 4;           // row group

    float acc[4][4];
    #pragma unroll
    for (int i = 0; i < 4; ++i)
        #pragma unroll
        for (int j = 0; j < 4; ++j) acc[i][j] = 0.f;

    // ---- staging helpers (register-buffered pipeline, single LDS buffer) ----
    float4 hbuf[2], wbuf[8];
    auto issue_loads = [&](int kc) {
        #pragma unroll
        for (int p = 0; p < 2; ++p) {
            int lin = tid + p * 256;           // 0..511
            int r   = lin >> 4;                // 0..31
            int kq  = (lin & 15) * 4;          // 0..60
            hbuf[p] = *(const float4*)(h + (size_t)(row0 + r) * F_IN + kc + kq);
        }
        #pragma unroll
        for (int p = 0; p < 8; ++p) {
            int lin = tid + p * 256;           // 0..2047
            int kr  = lin >> 5;                // 0..63
            int cq  = (lin & 31) * 4;          // 0..124
            wbuf[p] = *(const float4*)(W + (size_t)(kc + kr) * F_OUT + cq);
        }
    };
    auto commit_lds = [&]() {
        #pragma unroll
        for (int p = 0; p < 2; ++p) {
            int lin = tid + p * 256;
            int r   = lin >> 4;
            int kq  = (lin & 15) * 4;
            *(float4*)(h_tile + r * HPAD + kq) = hbuf[p];
        }
        #pragma unroll
        for (int p = 0; p < 8; ++p) {
            int lin = tid + p * 256;
            int kr  = lin >> 5;
            int cq  = (lin & 31) * 4;
            *(float4*)(W_tile + kr * F_OUT + cq) = wbuf[p];
        }
    };

    issue_loads(0);
    commit_lds();
    __syncthreads();

    #pragma unroll
    for (int ch = 0; ch < F_IN / KC; ++ch) {
        if (ch + 1 < F_IN / KC) issue_loads((ch + 1) * KC);   // prefetch into regs

        #pragma unroll
        for (int k4 = 0; k4 < KC; k4 += 4) {
            float4 hv[4], wv[4];
            #pragma unroll
            for (int i = 0; i < 4; ++i)
                hv[i] = *(const float4*)(h_tile + (r0 + i) * HPAD + k4);
            #pragma unroll
            for (int kk = 0; kk < 4; ++kk)
                wv[kk] = *(const float4*)(W_tile + (k4 + kk) * F_OUT + c0);
            #pragma unroll
            for (int i = 0; i < 4; ++i) {
                const float hv0[4] = {hv[i].x, hv[i].y, hv[i].z, hv[i].w};
                #pragma unroll
                for (int kk = 0; kk < 4; ++kk) {
                    acc[i][0] = fmaf(hv0[kk], wv[kk].x, acc[i][0]);
                    acc[i][1] = fmaf(hv0[kk], wv[kk].y, acc[i][1]);
                    acc[i][2] = fmaf(hv0[kk], wv[kk].z, acc[i][2]);
                    acc[i][3] = fmaf(hv0[kk], wv[kk].w, acc[i][3]);
                }
            }
        }
        __syncthreads();
        if (ch + 1 < F_IN / KC) {
            commit_lds();
            __syncthreads();
        }
    }

    // ---- store hW ----
    #pragma unroll
    for (int i = 0; i < 4; ++i) {
        float4 v = make_float4(acc[i][0], acc[i][1], acc[i][2], acc[i][3]);
        *(float4*)(hW + (size_t)(row0 + r0 + i) * F_OUT + c0) = v;
    }

    // ---- fused h1/h2: per-row dot with a1/a2, reduce across 32 col-lanes ----
    float a1v[4], a2v[4];
    #pragma unroll
    for (int j = 0; j < 4; ++j) {
        a1v[j] = a[c0 + j];
        a2v[j] = a[F_OUT + c0 + j];
    }
    #pragma unroll
    for (int i = 0; i < 4; ++i) {
        float s1 = 0.f, s2 = 0.f;
        #pragma unroll
        for (int j = 0; j < 4; ++j) {
            s1 = fmaf(acc[i][j], a1v[j], s1);
            s2 = fmaf(acc[i][j], a2v[j], s2);
        }
        #pragma unroll
        for (int off = 1; off < 32; off <<= 1) {
            s1 += __shfl_xor(s1, off);
            s2 += __shfl_xor(s2, off);
        }
        if ((tid & 31) == 0) {
            h1[row0 + r0 + i] = s1;
            h2[row0 + r0 + i] = s2;
        }
    }
}

// ---- Kernel C: sparse masked softmax + aggregation + ELU --------------------
// one wave per row; lanes 0..31 = neighbor slots, lane 32 = self entry.
__global__ __launch_bounds__(256) void attn_kernel(
        const float* __restrict__ hW,
        const float* __restrict__ h1,
        const float* __restrict__ h2,
        const int*   __restrict__ nbr,
        float* __restrict__ out) {
    const int wave = threadIdx.x >> 6;
    const int lane = threadIdx.x & 63;
    const int row  = blockIdx.x * 4 + wave;

    int col = -1;
    if (lane < DEG)       col = nbr[(size_t)row * DEG + lane];
    else if (lane == DEG) col = row;

    // dedup + multiplicity over the 33 candidate slots (scatter-add semantics)
    int cnt = 0;
    int firstq = lane;
    #pragma unroll
    for (int q = 0; q <= DEG; ++q) {
        int cq = __shfl(col, q);
        bool same = (cq == col);
        if (same && q < DEG)    cnt++;
        if (same && q < firstq) firstq = q;
    }
    const bool active = (lane <= DEG) && (col >= 0) && (firstq == lane);

    float mask_val = (float)cnt * (1.0f / 64.0f) + ((col == row) ? 0.5f : 0.0f);

    const float h1row = h1[row];
    float h2c = active ? h2[col] : 0.f;
    float s = mask_val * (h1row + h2c);
    float e = (s > 0.f) ? s : ALPHA * s;            // LeakyReLU
    bool valid = active && (e != 0.0f);             // e==0 -> NEG_INF in ref

    float ev = valid ? e : -INFINITY;
    #pragma unroll
    for (int off = 32; off > 0; off >>= 1)
        ev = fmaxf(ev, __shfl_xor(ev, off));
    float w = valid ? __expf(e - ev) : 0.f;
    float denom = w;
    #pragma unroll
    for (int off = 32; off > 0; off >>= 1)
        denom += __shfl_xor(denom, off);
    float att = w / denom;

    // aggregate: float2 gathers (512 B per candidate row)
    float acc0 = 0.f, acc1 = 0.f;
    #pragma unroll
    for (int q = 0; q <= DEG; ++q) {
        float aq = __shfl(att, q);
        int   cq = __shfl(col, q);
        if (aq > 0.f) {                              // wave-uniform branch
            float2 v = *(const float2*)(hW + (size_t)cq * F_OUT + 2 * lane);
            acc0 = fmaf(aq, v.x, acc0);
            acc1 = fmaf(aq, v.y, acc1);
        }
    }

    float o0 = (acc0 > 0.f) ? acc0 : (__expf(acc0) - 1.0f);
    float o1 = (acc1 > 0.f) ? acc1 : (__expf(acc1) - 1.0f);
    *(float2*)(out + (size_t)row * F_OUT + 2 * lane) = make_float2(o0, o1);
}

// -----------------------------------------------------------------------------
extern "C" void kernel_launch(void* const* d_in, const int* in_sizes, int n_in,
                              void* d_out, int out_size, void* d_ws, size_t ws_size,
                              hipStream_t stream) {
    const float* h   = (const float*)d_in[0];   // [8192, 256]
    const float* W   = (const float*)d_in[1];   // [256, 128]
    const float* a   = (const float*)d_in[2];   // [256, 1]
    const int*   nbr = (const int*)  d_in[3];   // [8192, 32]
    float* out = (float*)d_out;                 // [8192, 128]

    float* hW = (float*)d_ws;                   // 4 MB
    float* h1 = hW + (size_t)N_NODES * F_OUT;   // 32 KB
    float* h2 = h1 + N_NODES;                   // 32 KB

    gemm_fused_kernel<<<N_NODES / MT, 256, 0, stream>>>(h, W, a, hW, h1, h2);
    attn_kernel      <<<N_NODES / 4,  256, 0, stream>>>(hW, h1, h2, nbr, out);
}

// Round 4
// 94.208 us; speedup vs baseline: 1.2066x; 1.2066x over previous
//
#include <hip/hip_runtime.h>
#include <math.h>

#define N_NODES 8192
#define F_IN    256
#define F_OUT   128
#define DEG     32
#define ALPHA   0.2f

#define BR      16          // rows per block (GEMM)
#define KC      32          // k-chunk
#define HP      36          // h tile padded stride (floats): 36%32=4 -> conflict-free rows
#define NCHUNK  (F_IN / KC) // 8

typedef const uint32_t __attribute__((address_space(1)))* gas_ptr;
typedef uint32_t __attribute__((address_space(3)))* las_ptr;

// async 16B-per-lane global->LDS. g must be PER-LANE (base + lane*16B);
// LDS dest is wave-uniform base, HW writes base + lane*16.
__device__ __forceinline__ void async_copy16(const float* g, float* l) {
    __builtin_amdgcn_global_load_lds((gas_ptr)g, (las_ptr)l, 16, 0, 0);
}

__device__ __forceinline__ unsigned short f2bf(float x) {   // RNE f32->bf16
    unsigned u = __float_as_uint(x);
    return (unsigned short)((u + 0x7fffu + ((u >> 16) & 1u)) >> 16);
}

// ---- Kernel A: hW(bf16) = h @ W, fused h1/h2 epilogue -----------------------
// 512 blocks x 256 thr. Block: 16 rows x 128 cols. Thread: 2 rows x 4 cols.
// LDS double-buffered: hT[2][16*36] + wT[2][32*128] = ~37 KB.
__global__ __launch_bounds__(256) void gemm_fused_v4(
        const float* __restrict__ h,
        const float* __restrict__ W,
        const float* __restrict__ a,
        unsigned int* __restrict__ hWb,   // bf16 pairs, [8192][64] uints
        float* __restrict__ h1,
        float* __restrict__ h2) {
    __shared__ float hT[2][BR * HP];
    __shared__ float wT[2][KC * F_OUT];

    const int tid  = threadIdx.x;
    const int wv   = tid >> 6;            // wave 0..3
    const int lane = tid & 63;
    const int cg   = tid & 31;            // col group
    const int rg   = tid >> 5;            // row group 0..7
    const int c0   = cg * 4;
    const int r0   = rg * 2;
    const int row0 = blockIdx.x * BR;

    float acc[2][4] = {{0.f,0.f,0.f,0.f},{0.f,0.f,0.f,0.f}};

    // --- staging helpers ---
    // W chunk: 32x128 floats = 16 KB contiguous; wave wv copies 4 KB
    // (4 iters x 64 lanes x 16 B). Global src is PER-LANE (+lane*4 floats).
    auto stage_w = [&](int k0, int buf) {
        const float* gsrc = W + (size_t)k0 * F_OUT + wv * 1024 + lane * 4;
        float*       ldst = wT[buf] + wv * 1024;
        #pragma unroll
        for (int it = 0; it < 4; ++it)
            async_copy16(gsrc + it * 256, ldst + it * 256);
    };
    // h chunk: 16 rows x 32 k; threads 0..127 load one float4 each
    const int hrow = tid >> 3;            // 0..15 (tid<128)
    const int hkq  = (tid & 7) * 4;       // 0..28
    auto load_h = [&](int k0) -> float4 {
        if (tid < 128)
            return *(const float4*)(h + (size_t)(row0 + hrow) * F_IN + k0 + hkq);
        return make_float4(0.f, 0.f, 0.f, 0.f);
    };
    auto commit_h = [&](float4 v, int buf) {
        if (tid < 128)
            *(float4*)(hT[buf] + hrow * HP + hkq) = v;
    };

    // --- prologue: chunk 0 into buffer 0 ---
    stage_w(0, 0);
    commit_h(load_h(0), 0);
    __syncthreads();

    for (int ch = 0; ch < NCHUNK; ++ch) {
        const int cur = ch & 1, nxt = cur ^ 1;
        float4 hv_next;
        if (ch + 1 < NCHUNK) {
            stage_w((ch + 1) * KC, nxt);          // async, drains at barrier
            hv_next = load_h((ch + 1) * KC);
        }

        const float* hc = hT[cur];
        const float* wc = wT[cur];
        #pragma unroll
        for (int k4 = 0; k4 < KC; k4 += 4) {
            float4 h0 = *(const float4*)(hc + (r0    ) * HP + k4);
            float4 h1v= *(const float4*)(hc + (r0 + 1) * HP + k4);
            const float h0a[4] = {h0.x, h0.y, h0.z, h0.w};
            const float h1a[4] = {h1v.x, h1v.y, h1v.z, h1v.w};
            #pragma unroll
            for (int kk = 0; kk < 4; ++kk) {
                float4 wvv = *(const float4*)(wc + (k4 + kk) * F_OUT + c0);
                acc[0][0] = fmaf(h0a[kk], wvv.x, acc[0][0]);
                acc[0][1] = fmaf(h0a[kk], wvv.y, acc[0][1]);
                acc[0][2] = fmaf(h0a[kk], wvv.z, acc[0][2]);
                acc[0][3] = fmaf(h0a[kk], wvv.w, acc[0][3]);
                acc[1][0] = fmaf(h1a[kk], wvv.x, acc[1][0]);
                acc[1][1] = fmaf(h1a[kk], wvv.y, acc[1][1]);
                acc[1][2] = fmaf(h1a[kk], wvv.z, acc[1][2]);
                acc[1][3] = fmaf(h1a[kk], wvv.w, acc[1][3]);
            }
        }

        if (ch + 1 < NCHUNK) commit_h(hv_next, nxt);
        __syncthreads();                           // drains vmcnt (async W) + lgkm
    }

    // --- store hW as bf16 pairs (uint2 = 4 cols) ---
    #pragma unroll
    for (int i = 0; i < 2; ++i) {
        uint2 p;
        p.x = (unsigned)f2bf(acc[i][0]) | ((unsigned)f2bf(acc[i][1]) << 16);
        p.y = (unsigned)f2bf(acc[i][2]) | ((unsigned)f2bf(acc[i][3]) << 16);
        *(uint2*)(hWb + (size_t)(row0 + r0 + i) * (F_OUT / 2) + c0 / 2) = p;
    }

    // --- fused h1/h2 from f32 accumulators ---
    float4 a1 = *(const float4*)(a + c0);
    float4 a2 = *(const float4*)(a + F_OUT + c0);
    #pragma unroll
    for (int i = 0; i < 2; ++i) {
        float s1 = acc[i][0]*a1.x + acc[i][1]*a1.y + acc[i][2]*a1.z + acc[i][3]*a1.w;
        float s2 = acc[i][0]*a2.x + acc[i][1]*a2.y + acc[i][2]*a2.z + acc[i][3]*a2.w;
        #pragma unroll
        for (int off = 1; off < 32; off <<= 1) {
            s1 += __shfl_xor(s1, off);             // reduces within 32-lane half
            s2 += __shfl_xor(s2, off);
        }
        if (cg == 0) {
            h1[row0 + r0 + i] = s1;
            h2[row0 + r0 + i] = s2;
        }
    }
}

// ---- Kernel C: sparse masked softmax + bf16 aggregation + ELU ---------------
// one wave per row; lanes 0..31 = neighbor slots, lane 32 = self entry.
__global__ __launch_bounds__(256) void attn_kernel(
        const unsigned int* __restrict__ hWb,      // bf16 pairs
        const float* __restrict__ h1,
        const float* __restrict__ h2,
        const int*   __restrict__ nbr,
        float* __restrict__ out) {
    const int wave = threadIdx.x >> 6;
    const int lane = threadIdx.x & 63;
    const int row  = blockIdx.x * 4 + wave;

    int col = -1;
    if (lane < DEG)       col = nbr[(size_t)row * DEG + lane];
    else if (lane == DEG) col = row;

    // dedup + multiplicity over the 33 candidate slots (scatter-add semantics)
    int cnt = 0;
    int firstq = lane;
    #pragma unroll
    for (int q = 0; q <= DEG; ++q) {
        int cq = __shfl(col, q);
        bool same = (cq == col);
        if (same && q < DEG)    cnt++;
        if (same && q < firstq) firstq = q;
    }
    const bool active = (lane <= DEG) && (col >= 0) && (firstq == lane);

    float mask_val = (float)cnt * (1.0f / 64.0f) + ((col == row) ? 0.5f : 0.0f);

    const float h1row = h1[row];
    float h2c = active ? h2[col] : 0.f;
    float s = mask_val * (h1row + h2c);
    float e = (s > 0.f) ? s : ALPHA * s;            // LeakyReLU
    bool valid = active && (e != 0.0f);             // e==0 -> NEG_INF in ref

    float ev = valid ? e : -INFINITY;
    #pragma unroll
    for (int off = 32; off > 0; off >>= 1)
        ev = fmaxf(ev, __shfl_xor(ev, off));
    float w = valid ? __expf(e - ev) : 0.f;
    float denom = w;
    #pragma unroll
    for (int off = 32; off > 0; off >>= 1)
        denom += __shfl_xor(denom, off);
    float att = w / denom;

    // aggregate: 4 B bf16x2 gathers (256 B per candidate row)
    float acc0 = 0.f, acc1 = 0.f;
    #pragma unroll
    for (int q = 0; q <= DEG; ++q) {
        float aq = __shfl(att, q);
        int   cq = __shfl(col, q);
        if (aq > 0.f) {                              // wave-uniform branch
            unsigned v = hWb[(size_t)cq * (F_OUT / 2) + lane];
            float lo = __uint_as_float(v << 16);             // col 2*lane
            float hi = __uint_as_float(v & 0xffff0000u);     // col 2*lane+1
            acc0 = fmaf(aq, lo, acc0);
            acc1 = fmaf(aq, hi, acc1);
        }
    }

    float o0 = (acc0 > 0.f) ? acc0 : expm1f(acc0);
    float o1 = (acc1 > 0.f) ? acc1 : expm1f(acc1);
    *(float2*)(out + (size_t)row * F_OUT + 2 * lane) = make_float2(o0, o1);
}

// -----------------------------------------------------------------------------
extern "C" void kernel_launch(void* const* d_in, const int* in_sizes, int n_in,
                              void* d_out, int out_size, void* d_ws, size_t ws_size,
                              hipStream_t stream) {
    const float* h   = (const float*)d_in[0];   // [8192, 256]
    const float* W   = (const float*)d_in[1];   // [256, 128]
    const float* a   = (const float*)d_in[2];   // [256, 1]
    const int*   nbr = (const int*)  d_in[3];   // [8192, 32]
    float* out = (float*)d_out;                 // [8192, 128]

    // ws: hWb bf16 [8192*128] (2 MB) | h1 (32 KB) | h2 (32 KB)
    unsigned int* hWb = (unsigned int*)d_ws;
    float* h1 = (float*)(hWb + (size_t)N_NODES * (F_OUT / 2));
    float* h2 = h1 + N_NODES;

    gemm_fused_v4<<<N_NODES / BR, 256, 0, stream>>>(h, W, a, hWb, h1, h2);
    attn_kernel  <<<N_NODES / 4,  256, 0, stream>>>(hWb, h1, h2, nbr, out);
}

// Round 6
// 94.035 us; speedup vs baseline: 1.2088x; 1.0018x over previous
//
#include <hip/hip_runtime.h>
#include <math.h>

#define N_NODES 8192
#define F_IN    256
#define F_OUT   128
#define DEG     32
#define ALPHA   0.2f

typedef __attribute__((ext_vector_type(8))) short short8;   // 8 bf16 = 4 VGPR
typedef __attribute__((ext_vector_type(4))) float floatx4;  // MFMA acc

__device__ __forceinline__ unsigned short f2bf(float x) {   // RNE f32->bf16
    unsigned u = __float_as_uint(x);
    return (unsigned short)((u + 0x7fffu + ((u >> 16) & 1u)) >> 16);
}

// ---- Kernel P: pack W [256][128] f32 -> bf16 B-fragments, fragment-major ----
// frag f = kt*8 + gnt covers k in [kt*32,+32), n in [gnt*16,+16).
// B-frag layout: lane holds B[k = quad*8+j][n = lane&15], j=0..7.
// (verified working in v5 — v5's failure was score precision, not layout)
__global__ __launch_bounds__(64) void pack_w_kernel(
        const float* __restrict__ W, unsigned short* __restrict__ Wtf) {
    const int lane = threadIdx.x;          // 0..63
    const int quad = lane >> 4;
    const int l15  = lane & 15;
    const int kt   = blockIdx.x >> 3;
    const int gnt  = blockIdx.x & 7;
    const int n    = gnt * 16 + l15;
    const int kb   = kt * 32 + quad * 8;

    unsigned short s[8];
    #pragma unroll
    for (int j = 0; j < 8; ++j)
        s[j] = f2bf(W[(size_t)(kb + j) * F_OUT + n]);

    uint4 p;
    p.x = (unsigned)s[0] | ((unsigned)s[1] << 16);
    p.y = (unsigned)s[2] | ((unsigned)s[3] << 16);
    p.z = (unsigned)s[4] | ((unsigned)s[5] << 16);
    p.w = (unsigned)s[6] | ((unsigned)s[7] << 16);
    ((uint4*)Wtf)[(size_t)blockIdx.x * 64 + lane] = p;
}

// ---- Kernel W: wa1 = W @ a[:128], wa2 = W @ a[128:]  (f32, for exact scores)
__global__ __launch_bounds__(64) void wa_kernel(
        const float* __restrict__ W, const float* __restrict__ a,
        float* __restrict__ wa1, float* __restrict__ wa2) {
    const int k = blockIdx.x * 64 + threadIdx.x;      // 0..255
    const float* wr = W + (size_t)k * F_OUT;
    float s1 = 0.f, s2 = 0.f;
    #pragma unroll 4
    for (int n = 0; n < F_OUT; n += 4) {
        float4 wv = *(const float4*)(wr + n);
        float4 a1 = *(const float4*)(a + n);
        float4 a2 = *(const float4*)(a + F_OUT + n);
        s1 = fmaf(wv.x, a1.x, fmaf(wv.y, a1.y, fmaf(wv.z, a1.z, fmaf(wv.w, a1.w, s1))));
        s2 = fmaf(wv.x, a2.x, fmaf(wv.y, a2.y, fmaf(wv.z, a2.z, fmaf(wv.w, a2.w, s2))));
    }
    wa1[k] = s1;
    wa2[k] = s2;
}

// ---- Kernel A: hW(bf16) = h @ W via MFMA; h1/h2 from f32 h · (W@a) ----------
// 512 blocks x 256 thr (4 waves). Block: 16 rows x 128 cols.
// wave w covers cols [w*32, w*32+32) = 2 C-tiles. A-frag shared (same 16 rows).
// No LDS, no barriers. Wave 0 additionally computes f32 h1/h2.
__global__ __launch_bounds__(256) void gemm_mfma_v6(
        const float* __restrict__ h,
        const unsigned short* __restrict__ Wtf,
        const float* __restrict__ wa1,
        const float* __restrict__ wa2,
        unsigned short* __restrict__ hWb,   // [8192][128] bf16
        float* __restrict__ h1,
        float* __restrict__ h2) {
    const int tid  = threadIdx.x;
    const int wave = tid >> 6;             // 0..3 = col quarter
    const int lane = tid & 63;
    const int quad = lane >> 4;
    const int l15  = lane & 15;
    const int row0 = blockIdx.x * 16;

    const float* hrow = h + (size_t)(row0 + l15) * F_IN + quad * 8;
    const short8* Wf  = (const short8*)Wtf;

    floatx4 acc[2] = {{0.f,0.f,0.f,0.f},{0.f,0.f,0.f,0.f}};
    float s1 = 0.f, s2 = 0.f;

    #pragma unroll
    for (int kt = 0; kt < 8; ++kt) {
        float4 v0 = *(const float4*)(hrow + kt * 32);
        float4 v1 = *(const float4*)(hrow + kt * 32 + 4);
        short8 af;
        af[0] = (short)f2bf(v0.x); af[1] = (short)f2bf(v0.y);
        af[2] = (short)f2bf(v0.z); af[3] = (short)f2bf(v0.w);
        af[4] = (short)f2bf(v1.x); af[5] = (short)f2bf(v1.y);
        af[6] = (short)f2bf(v1.z); af[7] = (short)f2bf(v1.w);

        #pragma unroll
        for (int nt = 0; nt < 2; ++nt) {
            short8 bf = Wf[(size_t)(kt * 8 + wave * 2 + nt) * 64 + lane];
            acc[nt] = __builtin_amdgcn_mfma_f32_16x16x32_bf16(af, bf, acc[nt], 0, 0, 0);
        }

        if (wave == 0) {                   // f32 score path: s += h · wa
            const int kb = kt * 32 + quad * 8;
            float4 u0 = *(const float4*)(wa1 + kb);
            float4 u1 = *(const float4*)(wa1 + kb + 4);
            float4 t0 = *(const float4*)(wa2 + kb);
            float4 t1 = *(const float4*)(wa2 + kb + 4);
            s1 = fmaf(v0.x,u0.x, fmaf(v0.y,u0.y, fmaf(v0.z,u0.z, fmaf(v0.w,u0.w, s1))));
            s1 = fmaf(v1.x,u1.x, fmaf(v1.y,u1.y, fmaf(v1.z,u1.z, fmaf(v1.w,u1.w, s1))));
            s2 = fmaf(v0.x,t0.x, fmaf(v0.y,t0.y, fmaf(v0.z,t0.z, fmaf(v0.w,t0.w, s2))));
            s2 = fmaf(v1.x,t1.x, fmaf(v1.y,t1.y, fmaf(v1.z,t1.z, fmaf(v1.w,t1.w, s2))));
        }
    }

    // --- store hW bf16: C/D layout col=lane&15, row=quad*4+reg ---
    #pragma unroll
    for (int nt = 0; nt < 2; ++nt) {
        const int col = wave * 32 + nt * 16 + l15;
        #pragma unroll
        for (int reg = 0; reg < 4; ++reg) {
            const int row = row0 + quad * 4 + reg;
            hWb[(size_t)row * F_OUT + col] = f2bf(acc[nt][reg]);
        }
    }

    // --- h1/h2: reduce s1/s2 over the 4 quads (lanes l15, l15+16, +32, +48) --
    if (wave == 0) {
        s1 += __shfl_xor(s1, 16); s1 += __shfl_xor(s1, 32);
        s2 += __shfl_xor(s2, 16); s2 += __shfl_xor(s2, 32);
        if (lane < 16) {
            h1[row0 + l15] = s1;
            h2[row0 + l15] = s2;
        }
    }
}

// ---- Kernel C: sparse masked softmax + bf16 aggregation + ELU ---------------
// one wave per row; lanes 0..31 = neighbor slots, lane 32 = self entry.
__global__ __launch_bounds__(256) void attn_kernel(
        const unsigned int* __restrict__ hWb,      // bf16 pairs
        const float* __restrict__ h1,
        const float* __restrict__ h2,
        const int*   __restrict__ nbr,
        float* __restrict__ out) {
    const int wave = threadIdx.x >> 6;
    const int lane = threadIdx.x & 63;
    const int row  = blockIdx.x * 4 + wave;

    int col = -1;
    if (lane < DEG)       col = nbr[(size_t)row * DEG + lane];
    else if (lane == DEG) col = row;

    // dedup + multiplicity over the 33 candidate slots (scatter-add semantics)
    int cnt = 0;
    int firstq = lane;
    #pragma unroll
    for (int q = 0; q <= DEG; ++q) {
        int cq = __shfl(col, q);
        bool same = (cq == col);
        if (same && q < DEG)    cnt++;
        if (same && q < firstq) firstq = q;
    }
    const bool active = (lane <= DEG) && (col >= 0) && (firstq == lane);

    float mask_val = (float)cnt * (1.0f / 64.0f) + ((col == row) ? 0.5f : 0.0f);

    const float h1row = h1[row];
    float h2c = active ? h2[col] : 0.f;
    float s = mask_val * (h1row + h2c);
    float e = (s > 0.f) ? s : ALPHA * s;            // LeakyReLU
    bool valid = active && (e != 0.0f);             // e==0 -> NEG_INF in ref

    float ev = valid ? e : -INFINITY;
    #pragma unroll
    for (int off = 32; off > 0; off >>= 1)
        ev = fmaxf(ev, __shfl_xor(ev, off));
    float w = valid ? __expf(e - ev) : 0.f;
    float denom = w;
    #pragma unroll
    for (int off = 32; off > 0; off >>= 1)
        denom += __shfl_xor(denom, off);
    float att = w / denom;

    // aggregate: 4 B bf16x2 gathers (256 B per candidate row)
    float acc0 = 0.f, acc1 = 0.f;
    #pragma unroll
    for (int q = 0; q <= DEG; ++q) {
        float aq = __shfl(att, q);
        int   cq = __shfl(col, q);
        if (aq > 0.f) {                              // wave-uniform branch
            unsigned v = hWb[(size_t)cq * (F_OUT / 2) + lane];
            float lo = __uint_as_float(v << 16);             // col 2*lane
            float hi = __uint_as_float(v & 0xffff0000u);     // col 2*lane+1
            acc0 = fmaf(aq, lo, acc0);
            acc1 = fmaf(aq, hi, acc1);
        }
    }

    float o0 = (acc0 > 0.f) ? acc0 : expm1f(acc0);
    float o1 = (acc1 > 0.f) ? acc1 : expm1f(acc1);
    *(float2*)(out + (size_t)row * F_OUT + 2 * lane) = make_float2(o0, o1);
}

// -----------------------------------------------------------------------------
extern "C" void kernel_launch(void* const* d_in, const int* in_sizes, int n_in,
                              void* d_out, int out_size, void* d_ws, size_t ws_size,
                              hipStream_t stream) {
    const float* h   = (const float*)d_in[0];   // [8192, 256]
    const float* W   = (const float*)d_in[1];   // [256, 128]
    const float* a   = (const float*)d_in[2];   // [256, 1]
    const int*   nbr = (const int*)  d_in[3];   // [8192, 32]
    float* out = (float*)d_out;                 // [8192, 128]

    // ws: hWb bf16 (2 MB) | h1 (32 KB) | h2 (32 KB) | Wtf (64 KB) | wa1 | wa2
    unsigned short* hWb = (unsigned short*)d_ws;
    float* h1 = (float*)(hWb + (size_t)N_NODES * F_OUT);
    float* h2 = h1 + N_NODES;
    unsigned short* Wtf = (unsigned short*)(h2 + N_NODES);
    float* wa1 = (float*)(Wtf + (size_t)F_IN * F_OUT);
    float* wa2 = wa1 + F_IN;

    pack_w_kernel<<<64, 64, 0, stream>>>(W, Wtf);
    wa_kernel    <<<4,  64, 0, stream>>>(W, a, wa1, wa2);
    gemm_mfma_v6 <<<N_NODES / 16, 256, 0, stream>>>(h, Wtf, wa1, wa2, hWb, h1, h2);
    attn_kernel  <<<N_NODES / 4,  256, 0, stream>>>((const unsigned int*)hWb,
                                                    h1, h2, nbr, out);
}